// Round 4
// baseline (265.837 us; speedup 1.0000x reference)
//
#include <hip/hip_runtime.h>

// Trilinear grid_sample (align_corners=False, zeros padding) over a 128^3
// BINARY grid, 8.4M random points.
//
// R10: wave-specialized hybrid + fused prep.
//  R9 post-mortem: hybrid(72) ~= pure gather(76) because slab work and
//  gather TA time SERIALIZED (same waves issue both between the same
//  barriers; EXEC-masked j-loop 'continue' saves no issue slots). Fix:
//  role-split waves. Waves 0-7: slab fill + j-loop (8 pts/thr, first half
//  of points). Waves 8-15: table-gather (8 pts/thr, second half), batches
//  of 4 issued before barrier#1 / between #1-#2, consumed after #1 / #3.
//  Gather waves never touch LDS or fills -> their scattered-miss TA time
//  runs under slab compute. 3 top-level s_barriers, all waves.
//  Also: bitpack+table fused into prep_kernel (129 blocks, ballot 2 grid
//  planes into LDS bits -> mask plane + tbl plane), cutting a graph node
//  (R0 2-node gap 2.7us vs R7-9 3-node gap ~20us) and ~6us kernel time.

typedef float fx4 __attribute__((ext_vector_type(4)));
typedef unsigned int u32;
typedef unsigned int ux4 __attribute__((ext_vector_type(4)));
typedef unsigned long long u64;

constexpr int GS = 128;
constexpr size_t MASK_BYTES = (size_t)GS * GS * GS / 8;   // 256 KB
constexpr int SLAB_WORDS = 33281;
constexpr size_t SLAB_LDS = (size_t)SLAB_WORDS * 4;       // 133,124 B

constexpr int TD = GS + 1;                                 // 129
constexpr size_t TBL_BYTES = (size_t)TD * TD * TD;         // 2,146,689 B
constexpr size_t TBL_OFF   = (MASK_BYTES + 63) & ~(size_t)63;
constexpr size_t WS_FB     = TBL_OFF + TBL_BYTES;          // ~2.4 MB

constexpr int NPTS_FULL = 8388608;
constexpr int HGRP = NPTS_FULL / 2 / 8;                    // 524288 groups/half

// ---------------------------------------------------------- bitpack ------
// (kept only for the tiny-workspace fallback path)
__global__ __launch_bounds__(256)
void bitpack_kernel(const float* __restrict__ grid, u64* __restrict__ mask) {
    int gid = blockIdx.x * blockDim.x + threadIdx.x;   // 128^3 threads
    float v = grid[gid];
    u64 m = __ballot(v != 0.0f);
    if ((threadIdx.x & 63) == 0) mask[gid >> 6] = m;
}

__device__ __forceinline__ unsigned bit_at(u64 lo, u64 hi, int xi) {
    if ((unsigned)xi >= 128u) return 0u;
    u64 w = (xi < 64) ? lo : hi;
    return (unsigned)((w >> (xi & 63)) & 1ull);
}

// ------------------------------------------------- fused prep ------------
// Block b in [0,129): ballots grid planes b-1,b into LDS bits, writes
// mask plane z=b (b<128) and tbl plane zb=b (129x129 bytes).
__global__ __launch_bounds__(256)
void prep_kernel(const float* __restrict__ grid, u64* __restrict__ mask,
                 unsigned char* __restrict__ tbl) {
    __shared__ u64 bits[2][256];          // [plane][y*2 + xw]
    const int tid = threadIdx.x;
    const int b = blockIdx.x;
    const int wid = tid >> 6;
#pragma unroll
    for (int p = 0; p < 2; ++p) {
        int z = b - 1 + p;
        if ((unsigned)z < 128u) {
            for (int it = 0; it < 64; ++it) {   // 16384 floats / 256 thr
                float v = grid[z * 16384 + it * 256 + tid];
                u64 m = __ballot(v != 0.0f);
                if ((tid & 63) == 0) bits[p][it * 4 + wid] = m;
            }
        } else {
            bits[p][tid] = 0ull;
        }
    }
    __syncthreads();
    if (b < 128) mask[b * 256 + tid] = bits[1][tid];   // plane z=b
    for (int i = tid; i < TD * TD; i += 256) {
        int yb = i / TD, xb = i - yb * TD;             // [0,128]
        int x0 = xb - 1;
        unsigned byte = 0u;
#pragma unroll
        for (int p = 0; p < 2; ++p) {                  // z corner = b-1+p
#pragma unroll
            for (int dy = 0; dy < 2; ++dy) {
                int y = yb - 1 + dy;
                u64 lo = 0ull, hi = 0ull;
                if ((unsigned)y < 128u) { lo = bits[p][y * 2]; hi = bits[p][y * 2 + 1]; }
                int kk = dy * 2 + p * 4;
                byte |= (bit_at(lo, hi, x0) << kk) | (bit_at(lo, hi, x0 + 1) << (kk + 1));
            }
        }
        tbl[b * (TD * TD) + i] = (unsigned char)byte;
    }
}

// ------------------------------------------------- wave-specialized ------
// 1024 blocks x 1024 threads. Waves 0-7 (tid<512): slab, 8 pts/thread,
// first half. Waves 8-15: gather, 8 pts/thread, second half.
__global__ __attribute__((amdgpu_waves_per_eu(4, 4))) __launch_bounds__(1024)
void sample_ws(const u32* __restrict__ mask32,
               const unsigned char* __restrict__ tbl,
               const float* __restrict__ coords,
               float* __restrict__ out) {
    extern __shared__ u32 lds[];
    const int tid = threadIdx.x;
    const bool slab = tid < 512;
    const int T = blockIdx.x * 512 + (slab ? tid : (HGRP - 512 + tid));
    const fx4* c4 = (const fx4*)coords;

    fx4 q[6];
#pragma unroll
    for (int j = 0; j < 6; ++j) q[j] = __builtin_nontemporal_load(&c4[6 * T + j]);
    const float* f = (const float*)q;

    // unioned per-role state (both roles never coexist in one thread)
    float wx[8], wy[8], wz[8], o[8];
    u32 p1[8];        // slab: packed addr/shift/zb ; gather: table address
    u32 gb[8];        // gather: fetched bytes
    u32 AM = 0;

    if (slab) {
        // ---- slab prologue (R6 math, 8 points)
#pragma unroll
        for (int j = 0; j < 8; ++j) {
            float ix = fmaf(f[3 * j + 0], 64.0f, 63.5f);   // ((x+1)*128-1)/2
            float iy = fmaf(f[3 * j + 1], 64.0f, 63.5f);
            float iz = fmaf(f[3 * j + 2], 64.0f, 63.5f);
            float fx = floorf(ix), fy = floorf(iy), fz = floorf(iz);
            float w0 = ix - fx;
            wy[j] = iy - fy; wz[j] = iz - fz;
            int x0 = (int)fx, y0 = (int)fy, z0 = (int)fz;  // [-1,127]
            int zb = z0 + 1;                               // [0,128]
            bool flip = (x0 < 0);
            wx[j] = flip ? 1.0f - w0 : w0;
            int xc = flip ? 0 : x0;
            int sft = xc & 31;
            u32 xm = ((u32)x0 <= 126u) ? 3u : 1u;
            u32 vy0 = (u32)(y0 >= 0);
            u32 vy1 = (u32)((u32)y0 <= 126u);
            u32 a0 = vy0 ? xm : 0u;
            u32 a1 = vy1 ? xm : 0u;
            u32 am = a0 | (a1 << 2);
            u32 dyf = vy0 & vy1;
            int y0c = y0 < 0 ? 0 : y0;
            int z0c = z0 < 0 ? 0 : z0;
            u32 RA = (u32)(((z0c << 7) + y0c) * 4 + (xc >> 5));
            p1[j] = RA | ((u32)sft << 16) | ((u32)zb << 21) | (dyf << 29);
            AM |= am << (4 * j);
            o[j] = 0.0f;
        }
    } else {
        // ---- gather prologue: addresses + weights, issue batch0
#pragma unroll
        for (int i = 0; i < 8; ++i) {
            float ix = fmaf(f[3 * i + 0], 64.0f, 63.5f);
            float iy = fmaf(f[3 * i + 1], 64.0f, 63.5f);
            float iz = fmaf(f[3 * i + 2], 64.0f, 63.5f);
            float fx = floorf(ix), fy = floorf(iy), fz = floorf(iz);
            wx[i] = ix - fx; wy[i] = iy - fy; wz[i] = iz - fz;
            int xb = (int)fx + 1, yb = (int)fy + 1, zb = (int)fz + 1;  // [0,128]
            p1[i] = (u32)((zb * TD + yb) * TD + xb);
        }
#pragma unroll
        for (int i = 0; i < 4; ++i) gb[i] = (u32)tbl[p1[i]];   // batch0 in flight
    }

    // slab fill / j-loop helpers
    auto fill = [&](int s_) {
        const int base_w = s_ ? 32256 : 0;              // 63*512
        const int nv4    = s_ ? 8320 : 8192;
        const ux4* src = (const ux4*)(mask32 + base_w);
        ux4* dst = (ux4*)lds;
        for (int i = tid; i < nv4; i += 512) dst[i] = src[i];
        if (s_ && tid == 0) lds[33280] = 0;             // straddle pad
    };
    auto jloop = [&](int s_) {
        const int base_w = s_ ? 32256 : 0;
#pragma unroll
        for (int j = 0; j < 8; ++j) {
            u32 pv = p1[j];
            int zb = (int)((pv >> 21) & 0xFF);
            if ((zb < 64) != (s_ == 0)) continue;       // not this slab
            int la  = (int)(pv & 0xFFFF) - base_w;
            int sft = (int)((pv >> 16) & 31);
            int dyw = (int)((pv >> 27) & 4);
            bool edge = s_ ? (zb == 128) : (zb == 0);
            int dz = edge ? 0 : 512;
            u32 amv = (AM >> (4 * j)) & 15u;
            u32 glo = amv, ghi = amv;
            if (s_) ghi = edge ? 0u : amv;
            else    glo = edge ? 0u : amv;
            int l0 = la, l1 = la + dyw, l2 = la + dz, l3 = la + dz + dyw;
            u32 w00 = lds[l0], w01 = lds[l0 + 1];
            u32 w10 = lds[l1], w11 = lds[l1 + 1];
            u32 w20 = lds[l2], w21 = lds[l2 + 1];
            u32 w30 = lds[l3], w31 = lds[l3 + 1];
            u32 t0b = __builtin_amdgcn_alignbit(w01, w00, (u32)sft) & (glo & 3u);
            u32 t1b = __builtin_amdgcn_alignbit(w11, w10, (u32)sft) & ((glo >> 2) & 3u);
            u32 t2b = __builtin_amdgcn_alignbit(w21, w20, (u32)sft) & (ghi & 3u);
            u32 t3b = __builtin_amdgcn_alignbit(w31, w30, (u32)sft) & ((ghi >> 2) & 3u);
            float w = wx[j];
            int b0 = (int)(t0b & 1u), b1 = (int)(t1b & 1u);
            int b2 = (int)(t2b & 1u), b3 = (int)(t3b & 1u);
            float r00 = fmaf(w, (float)((int)(t0b >> 1) - b0), (float)b0);
            float r01 = fmaf(w, (float)((int)(t1b >> 1) - b1), (float)b1);
            float r10 = fmaf(w, (float)((int)(t2b >> 1) - b2), (float)b2);
            float r11 = fmaf(w, (float)((int)(t3b >> 1) - b3), (float)b3);
            float cy0 = fmaf(wy[j], r01 - r00, r00);
            float cy1 = fmaf(wy[j], r11 - r10, r10);
            o[j] = fmaf(wz[j], cy1 - cy0, cy0);
        }
    };
    auto consume = [&](int i0) {
#pragma unroll
        for (int k = 0; k < 4; ++k) {
            int i = i0 + k;
            unsigned byte = gb[i];
            float v0 = (float)( byte       & 1u);
            float v1 = (float)((byte >> 1) & 1u);
            float v2 = (float)((byte >> 2) & 1u);
            float v3 = (float)((byte >> 3) & 1u);
            float v4 = (float)((byte >> 4) & 1u);
            float v5 = (float)((byte >> 5) & 1u);
            float v6 = (float)((byte >> 6) & 1u);
            float v7 = (float)((byte >> 7) & 1u);
            float c00 = v0 + wx[i] * (v1 - v0);
            float c10 = v2 + wx[i] * (v3 - v2);
            float c01 = v4 + wx[i] * (v5 - v4);
            float c11 = v6 + wx[i] * (v7 - v6);
            float c0  = c00 + wy[i] * (c10 - c00);
            float c1  = c01 + wy[i] * (c11 - c01);
            o[i] = c0 + wz[i] * (c1 - c0);
        }
    };

    if (slab) {
        fill(0);
        asm volatile("s_waitcnt lgkmcnt(0)" ::: "memory");
    }
    __builtin_amdgcn_s_barrier();                      // #1
    if (slab) {
        jloop(0);
        asm volatile("s_waitcnt lgkmcnt(0)" ::: "memory");  // reads done pre-overwrite
    } else {
        consume(0);                                     // waits batch0 (compiler vmcnt)
#pragma unroll
        for (int i = 4; i < 8; ++i) gb[i] = (u32)tbl[p1[i]];   // batch1 in flight
    }
    __builtin_amdgcn_s_barrier();                      // #2
    if (slab) {
        fill(1);
        asm volatile("s_waitcnt lgkmcnt(0)" ::: "memory");
    }
    __builtin_amdgcn_s_barrier();                      // #3
    if (slab) jloop(1);
    else      consume(4);

    fx4* o4 = (fx4*)out;
    fx4 r0 = {o[0], o[1], o[2], o[3]};
    fx4 r1 = {o[4], o[5], o[6], o[7]};
    __builtin_nontemporal_store(r0, &o4[2 * T]);
    __builtin_nontemporal_store(r1, &o4[2 * T + 1]);
}

// ------------------------------------------------- fallback sampler ------
__global__ __launch_bounds__(256)
void sample_packed(const unsigned char* __restrict__ tbl,
                   const float* __restrict__ coords,
                   float* __restrict__ out, int nt) {
    int t = blockIdx.x * blockDim.x + threadIdx.x;
    if (t >= nt) return;
    const fx4* c4 = (const fx4*)coords;
    fx4 q[6];
#pragma unroll
    for (int j = 0; j < 6; ++j) q[j] = __builtin_nontemporal_load(&c4[6 * t + j]);
    const float* f = (const float*)q;
    float wxa[8], wya[8], wza[8];
    int addr[8];
#pragma unroll
    for (int i = 0; i < 8; ++i) {
        float ix = fmaf(f[3 * i + 0], 64.0f, 63.5f);
        float iy = fmaf(f[3 * i + 1], 64.0f, 63.5f);
        float iz = fmaf(f[3 * i + 2], 64.0f, 63.5f);
        float fx = floorf(ix), fy = floorf(iy), fz = floorf(iz);
        wxa[i] = ix - fx; wya[i] = iy - fy; wza[i] = iz - fz;
        int xb = (int)fx + 1, yb = (int)fy + 1, zb = (int)fz + 1;
        addr[i] = (zb * TD + yb) * TD + xb;
    }
    unsigned bytes[8];
#pragma unroll
    for (int i = 0; i < 8; ++i) bytes[i] = (unsigned)tbl[addr[i]];
    float o[8];
#pragma unroll
    for (int i = 0; i < 8; ++i) {
        unsigned byte = bytes[i];
        float wx = wxa[i], wy = wya[i], wz = wza[i];
        float v0 = (float)( byte       & 1u);
        float v1 = (float)((byte >> 1) & 1u);
        float v2 = (float)((byte >> 2) & 1u);
        float v3 = (float)((byte >> 3) & 1u);
        float v4 = (float)((byte >> 4) & 1u);
        float v5 = (float)((byte >> 5) & 1u);
        float v6 = (float)((byte >> 6) & 1u);
        float v7 = (float)((byte >> 7) & 1u);
        float c00 = v0 + wx * (v1 - v0);
        float c10 = v2 + wx * (v3 - v2);
        float c01 = v4 + wx * (v5 - v4);
        float c11 = v6 + wx * (v7 - v6);
        float c0  = c00 + wy * (c10 - c00);
        float c1  = c01 + wy * (c11 - c01);
        o[i] = c0 + wz * (c1 - c0);
    }
    fx4* o4 = (fx4*)out;
    fx4 r0 = {o[0], o[1], o[2], o[3]};
    fx4 r1 = {o[4], o[5], o[6], o[7]};
    __builtin_nontemporal_store(r0, &o4[2 * t + 0]);
    __builtin_nontemporal_store(r1, &o4[2 * t + 1]);
}

// ------------------------------------------------- fallback: LDS slab ----
__global__ __launch_bounds__(1024, 4)
void sample_2p(const u32* __restrict__ mask32,
               const float* __restrict__ coords,
               float* __restrict__ out) {
    extern __shared__ u32 lds[];
    const int tid = threadIdx.x;
    const int T = blockIdx.x * 1024 + tid;
    const fx4* c4 = (const fx4*)coords;
    fx4 q[6];
#pragma unroll
    for (int j = 0; j < 6; ++j) q[j] = c4[6 * T + j];
    const float* f = (const float*)q;
    u32 pack1[8];
    u32 AM = 0;
    float wx[8], wy[8], wz[8], o[8];
#pragma unroll
    for (int j = 0; j < 8; ++j) {
        float ix = fmaf(f[3 * j + 0], 64.0f, 63.5f);
        float iy = fmaf(f[3 * j + 1], 64.0f, 63.5f);
        float iz = fmaf(f[3 * j + 2], 64.0f, 63.5f);
        float fx = floorf(ix), fy = floorf(iy), fz = floorf(iz);
        float w0 = ix - fx;
        wy[j] = iy - fy; wz[j] = iz - fz;
        int x0 = (int)fx, y0 = (int)fy, z0 = (int)fz;
        int zb = z0 + 1;
        bool flip = (x0 < 0);
        wx[j] = flip ? 1.0f - w0 : w0;
        int xc = flip ? 0 : x0;
        int sft = xc & 31;
        u32 xm = ((u32)x0 <= 126u) ? 3u : 1u;
        u32 vy0 = (u32)(y0 >= 0);
        u32 vy1 = (u32)((u32)y0 <= 126u);
        u32 a0 = vy0 ? xm : 0u;
        u32 a1 = vy1 ? xm : 0u;
        u32 am = a0 | (a1 << 2);
        u32 dyf = vy0 & vy1;
        int y0c = y0 < 0 ? 0 : y0;
        int z0c = z0 < 0 ? 0 : z0;
        u32 RA = (u32)(((z0c << 7) + y0c) * 4 + (xc >> 5));
        pack1[j] = RA | ((u32)sft << 16) | ((u32)zb << 21) | (dyf << 29);
        AM |= am << (4 * j);
        o[j] = 0.0f;
    }
#pragma unroll 1
    for (int s = 0; s < 2; ++s) {
        const int base_w = s ? 32256 : 0;
        const int nv4    = s ? 8320 : 8192;
        __syncthreads();
        {
            const ux4* src = (const ux4*)(mask32 + base_w);
            ux4* dst = (ux4*)lds;
            for (int i = tid; i < nv4; i += 1024) dst[i] = src[i];
            if (s && tid == 0) lds[33280] = 0;
        }
        __syncthreads();
#pragma unroll
        for (int j = 0; j < 8; ++j) {
            u32 pv = pack1[j];
            int zb = (int)((pv >> 21) & 0xFF);
            if ((zb < 64) != (s == 0)) continue;
            int la  = (int)(pv & 0xFFFF) - base_w;
            int sft = (int)((pv >> 16) & 31);
            int dyw = (int)((pv >> 27) & 4);
            bool edge = s ? (zb == 128) : (zb == 0);
            int dz = edge ? 0 : 512;
            u32 amv = (AM >> (4 * j)) & 15u;
            u32 glo = amv, ghi = amv;
            if (s) ghi = edge ? 0u : amv;
            else   glo = edge ? 0u : amv;
            int l0 = la, l1 = la + dyw, l2 = la + dz, l3 = la + dz + dyw;
            u32 w00 = lds[l0], w01 = lds[l0 + 1];
            u32 w10 = lds[l1], w11 = lds[l1 + 1];
            u32 w20 = lds[l2], w21 = lds[l2 + 1];
            u32 w30 = lds[l3], w31 = lds[l3 + 1];
            u32 t0b = __builtin_amdgcn_alignbit(w01, w00, (u32)sft) & (glo & 3u);
            u32 t1b = __builtin_amdgcn_alignbit(w11, w10, (u32)sft) & ((glo >> 2) & 3u);
            u32 t2b = __builtin_amdgcn_alignbit(w21, w20, (u32)sft) & (ghi & 3u);
            u32 t3b = __builtin_amdgcn_alignbit(w31, w30, (u32)sft) & ((ghi >> 2) & 3u);
            float w = wx[j];
            int b0 = (int)(t0b & 1u), b1 = (int)(t1b & 1u);
            int b2 = (int)(t2b & 1u), b3 = (int)(t3b & 1u);
            float r00 = fmaf(w, (float)((int)(t0b >> 1) - b0), (float)b0);
            float r01 = fmaf(w, (float)((int)(t1b >> 1) - b1), (float)b1);
            float r10 = fmaf(w, (float)((int)(t2b >> 1) - b2), (float)b2);
            float r11 = fmaf(w, (float)((int)(t3b >> 1) - b3), (float)b3);
            float cy0 = fmaf(wy[j], r01 - r00, r00);
            float cy1 = fmaf(wy[j], r11 - r10, r10);
            o[j] = fmaf(wz[j], cy1 - cy0, cy0);
        }
    }
    fx4* o4 = (fx4*)out;
    fx4 r0 = {o[0], o[1], o[2], o[3]};
    fx4 r1 = {o[4], o[5], o[6], o[7]};
    o4[2 * T]     = r0;
    o4[2 * T + 1] = r1;
}

// -------------------------------------------------------------- launch ----
extern "C" void kernel_launch(void* const* d_in, const int* in_sizes, int n_in,
                              void* d_out, int out_size, void* d_ws, size_t ws_size,
                              hipStream_t stream) {
    const float* grid   = (const float*)d_in[0];
    const float* coords = (const float*)d_in[1];
    float* out = (float*)d_out;
    int npts = in_sizes[1] / 3;                          // 8,388,608
    int vox = GS * GS * GS;

    u64* mask = (u64*)d_ws;                              // 256 KB @ offset 0

    if (ws_size >= WS_FB && npts == NPTS_FULL) {
        // PRIMARY: fused prep + wave-specialized hybrid (2 nodes).
        (void)hipFuncSetAttribute((const void*)sample_ws,
                                  hipFuncAttributeMaxDynamicSharedMemorySize,
                                  (int)SLAB_LDS);
        int nb = 0;
        hipError_t oe = hipOccupancyMaxActiveBlocksPerMultiprocessor(
            &nb, sample_ws, 1024, SLAB_LDS);
        unsigned char* tbl = (unsigned char*)d_ws + TBL_OFF;
        prep_kernel<<<TD, 256, 0, stream>>>(grid, mask, tbl);
        if (oe == hipSuccess && nb >= 1) {
            sample_ws<<<1024, 1024, SLAB_LDS, stream>>>(
                (const u32*)mask, tbl, coords, out);
        } else {
            int nt = npts / 8;
            sample_packed<<<(nt + 255) / 256, 256, 0, stream>>>(tbl, coords, out, nt);
        }
        return;
    }

    if (ws_size >= WS_FB && (npts & 7) == 0) {
        // FALLBACK: prep + pure byte-table path.
        unsigned char* tbl = (unsigned char*)d_ws + TBL_OFF;
        prep_kernel<<<TD, 256, 0, stream>>>(grid, mask, tbl);
        int nt = npts / 8;
        sample_packed<<<(nt + 255) / 256, 256, 0, stream>>>(tbl, coords, out, nt);
        return;
    }

    if (ws_size >= MASK_BYTES && npts == 1024 * 8192) {
        // FALLBACK: tiny workspace — 2-pass LDS slab.
        (void)hipFuncSetAttribute((const void*)sample_2p,
                                  hipFuncAttributeMaxDynamicSharedMemorySize,
                                  (int)SLAB_LDS);
        int nb = 0;
        hipError_t oe = hipOccupancyMaxActiveBlocksPerMultiprocessor(
            &nb, sample_2p, 1024, SLAB_LDS);
        if (oe == hipSuccess && nb >= 1) {
            bitpack_kernel<<<vox / 256, 256, 0, stream>>>(grid, mask);
            sample_2p<<<1024, 1024, SLAB_LDS, stream>>>((const u32*)mask, coords, out);
        }
    }
}

// Round 5
// 224.598 us; speedup vs baseline: 1.1836x; 1.1836x over previous
//
#include <hip/hip_runtime.h>

// Trilinear grid_sample (align_corners=False, zeros padding) over a 128^3
// BINARY grid, 8.4M random points.
//
// R11: 2-node structure (measured: 2-node totals 194.4/194.8 vs 3-node
// 215.4/216.8 — the 3rd node costs ~21us of window) with:
//  prep2 (1 dispatch, 24833 blocks):
//    blocks [0,8192): bitpack ballot (proven 3us form).
//    blocks [8192,24833): one (zb,yb) table row each, bytes built DIRECTLY
//    from grid (8 predicated loads, L1/L2-resident, no mask dep, no
//    barrier). Fixes R10's prep disaster (129 blocks -> 5% occupancy,
//    63us latency-bound).
//  sample_hyb (512 blocks x 1024 thr, 8 slab + 8 gather pts/thread):
//    R9's proven same-wave hybrid skeleton (R10's wave-specialization
//    REGRESSED: barriers lockstep the roles). TA model: gather 91K cyc/CU
//    fixed; fill = blocks*512KB through same TA pipe -> 512 blocks halves
//    fill TA vs R9 (536->268MB). waves_per_eu(4,4) keeps 128-VGPR budget
//    (R8's spill was the 64-cap w/ dynamic LDS).

typedef float fx4 __attribute__((ext_vector_type(4)));
typedef unsigned int u32;
typedef unsigned int ux4 __attribute__((ext_vector_type(4)));
typedef unsigned long long u64;

constexpr int GS = 128;
constexpr size_t MASK_BYTES = (size_t)GS * GS * GS / 8;   // 256 KB
constexpr int SLAB_WORDS = 33281;
constexpr size_t SLAB_LDS = (size_t)SLAB_WORDS * 4;       // 133,124 B

constexpr int TD = GS + 1;                                 // 129
constexpr size_t TBL_BYTES = (size_t)TD * TD * TD;         // 2,146,689 B
constexpr size_t TBL_OFF   = (MASK_BYTES + 63) & ~(size_t)63;
constexpr size_t WS_FB     = TBL_OFF + TBL_BYTES;          // ~2.4 MB

constexpr int NPTS_FULL = 8388608;
constexpr int HGRP8 = NPTS_FULL / 2 / 8;                   // 524,288 groups/half

constexpr int PREP_BITPACK_BLOCKS = (GS * GS * GS) / 256;  // 8192
constexpr int PREP_TBL_BLOCKS = TD * TD;                   // 16641
constexpr int PREP_BLOCKS = PREP_BITPACK_BLOCKS + PREP_TBL_BLOCKS;

// ---------------------------------------------------------- fused prep ---
__global__ __launch_bounds__(256)
void prep2_kernel(const float* __restrict__ grid, u64* __restrict__ mask,
                  unsigned char* __restrict__ tbl) {
    const int b = blockIdx.x, tid = threadIdx.x;
    if (b < PREP_BITPACK_BLOCKS) {
        // bitpack: 1 float/thread, ballot per wave (proven form)
        int gid = b * 256 + tid;
        float v = grid[gid];
        u64 m = __ballot(v != 0.0f);
        if ((tid & 63) == 0) mask[gid >> 6] = m;
        return;
    }
    // table row (zb,yb): 129 bytes along xb, direct from grid
    int rb = b - PREP_BITPACK_BLOCKS;          // [0, 129*129)
    int zb = rb / TD, yb = rb - zb * TD;       // [0,128]
    int xb = tid;
    if (xb >= TD) return;
    int z0 = zb - 1, y0 = yb - 1, x0 = xb - 1;
    unsigned byte = 0u;
#pragma unroll
    for (int dz = 0; dz < 2; ++dz) {
        int z = z0 + dz;
        bool zin = (unsigned)z < 128u;
#pragma unroll
        for (int dy = 0; dy < 2; ++dy) {
            int y = y0 + dy;
            bool yin = zin && ((unsigned)y < 128u);
            const float* row = grid + ((z * 128 + y) * 128);
#pragma unroll
            for (int dx = 0; dx < 2; ++dx) {
                int x = x0 + dx;
                unsigned bit = 0u;
                if (yin && ((unsigned)x < 128u)) bit = (row[x] != 0.0f) ? 1u : 0u;
                byte |= bit << (dx + 2 * dy + 4 * dz);
            }
        }
    }
    tbl[rb * TD + xb] = (unsigned char)byte;
}

// ---------------------------------------------------------- bitpack ------
// (tiny-workspace fallback only)
__global__ __launch_bounds__(256)
void bitpack_kernel(const float* __restrict__ grid, u64* __restrict__ mask) {
    int gid = blockIdx.x * blockDim.x + threadIdx.x;
    float v = grid[gid];
    u64 m = __ballot(v != 0.0f);
    if ((threadIdx.x & 63) == 0) mask[gid >> 6] = m;
}

// ------------------------------------------------- same-wave hybrid ------
// 512 blocks x 1024 threads. Each thread: 8 slab pts (group Ts, first half
// of points) + 8 gather pts (group Tg, second half).
__global__ __attribute__((amdgpu_waves_per_eu(4, 4))) __launch_bounds__(1024)
void sample_hyb(const u32* __restrict__ mask32,
                const unsigned char* __restrict__ tbl,
                const float* __restrict__ coords,
                float* __restrict__ out) {
    extern __shared__ u32 lds[];
    const int tid = threadIdx.x;
    const int Ts = blockIdx.x * 1024 + tid;            // slab group id
    const int Tg = Ts + HGRP8;                         // gather group id
    const fx4* c4 = (const fx4*)coords;

    fx4 qg[6];
#pragma unroll
    for (int j = 0; j < 6; ++j) qg[j] = __builtin_nontemporal_load(&c4[6 * Tg + j]);
    const float* fg = (const float*)qg;

    // ---- slab prologue (R6 math, 8 points); qs dies after this block
    u32 pack1[8];
    u32 AM = 0;
    float wx[8], wy[8], wz[8], o[8];
    {
        fx4 qs[6];
#pragma unroll
        for (int j = 0; j < 6; ++j) qs[j] = __builtin_nontemporal_load(&c4[6 * Ts + j]);
        const float* f = (const float*)qs;
#pragma unroll
        for (int j = 0; j < 8; ++j) {
            float ix = fmaf(f[3 * j + 0], 64.0f, 63.5f);   // ((x+1)*128-1)/2
            float iy = fmaf(f[3 * j + 1], 64.0f, 63.5f);
            float iz = fmaf(f[3 * j + 2], 64.0f, 63.5f);
            float fx = floorf(ix), fy = floorf(iy), fz = floorf(iz);
            float w0 = ix - fx;
            wy[j] = iy - fy; wz[j] = iz - fz;
            int x0 = (int)fx, y0 = (int)fy, z0 = (int)fz;  // [-1,127]
            int zb = z0 + 1;                               // [0,128]
            bool flip = (x0 < 0);
            wx[j] = flip ? 1.0f - w0 : w0;
            int xc = flip ? 0 : x0;
            int sft = xc & 31;
            u32 xm = ((u32)x0 <= 126u) ? 3u : 1u;
            u32 vy0 = (u32)(y0 >= 0);
            u32 vy1 = (u32)((u32)y0 <= 126u);
            u32 a0 = vy0 ? xm : 0u;
            u32 a1 = vy1 ? xm : 0u;
            u32 am = a0 | (a1 << 2);
            u32 dyf = vy0 & vy1;
            int y0c = y0 < 0 ? 0 : y0;
            int z0c = z0 < 0 ? 0 : z0;
            u32 RA = (u32)(((z0c << 7) + y0c) * 4 + (xc >> 5));
            pack1[j] = RA | ((u32)sft << 16) | ((u32)zb << 21) | (dyf << 29);
            AM |= am << (4 * j);
            o[j] = 0.0f;
        }
    }

    u32 gb[8];

    auto jloop = [&](int s_) {
        const int base_w = s_ ? 32256 : 0;
#pragma unroll
        for (int j = 0; j < 8; ++j) {
            u32 pv = pack1[j];
            int zb = (int)((pv >> 21) & 0xFF);
            if ((zb < 64) != (s_ == 0)) continue;       // not this slab
            int la  = (int)(pv & 0xFFFF) - base_w;
            int sft = (int)((pv >> 16) & 31);
            int dyw = (int)((pv >> 27) & 4);
            bool edge = s_ ? (zb == 128) : (zb == 0);
            int dz = edge ? 0 : 512;
            u32 amv = (AM >> (4 * j)) & 15u;
            u32 glo = amv, ghi = amv;
            if (s_) ghi = edge ? 0u : amv;
            else    glo = edge ? 0u : amv;
            int l0 = la, l1 = la + dyw, l2 = la + dz, l3 = la + dz + dyw;
            u32 w00 = lds[l0], w01 = lds[l0 + 1];
            u32 w10 = lds[l1], w11 = lds[l1 + 1];
            u32 w20 = lds[l2], w21 = lds[l2 + 1];
            u32 w30 = lds[l3], w31 = lds[l3 + 1];
            u32 t0b = __builtin_amdgcn_alignbit(w01, w00, (u32)sft) & (glo & 3u);
            u32 t1b = __builtin_amdgcn_alignbit(w11, w10, (u32)sft) & ((glo >> 2) & 3u);
            u32 t2b = __builtin_amdgcn_alignbit(w21, w20, (u32)sft) & (ghi & 3u);
            u32 t3b = __builtin_amdgcn_alignbit(w31, w30, (u32)sft) & ((ghi >> 2) & 3u);
            float w = wx[j];
            int b0 = (int)(t0b & 1u), b1 = (int)(t1b & 1u);
            int b2 = (int)(t2b & 1u), b3 = (int)(t3b & 1u);
            float r00 = fmaf(w, (float)((int)(t0b >> 1) - b0), (float)b0);
            float r01 = fmaf(w, (float)((int)(t1b >> 1) - b1), (float)b1);
            float r10 = fmaf(w, (float)((int)(t2b >> 1) - b2), (float)b2);
            float r11 = fmaf(w, (float)((int)(t3b >> 1) - b3), (float)b3);
            float cy0 = fmaf(wy[j], r01 - r00, r00);
            float cy1 = fmaf(wy[j], r11 - r10, r10);
            o[j] = fmaf(wz[j], cy1 - cy0, cy0);
        }
    };

    // ================= pass A =================
    {
        const ux4* src = (const ux4*)mask32;
        ux4* dst = (ux4*)lds;
#pragma unroll
        for (int i = 0; i < 8; ++i) dst[tid + 1024 * i] = src[tid + 1024 * i];
    }
    // gather batch 0: issued after fill loads/stores -> stays in flight
    // across the raw barriers (lgkmcnt-only waits) under jloop(0)
#pragma unroll
    for (int i = 0; i < 4; ++i) {
        float ix = fmaf(fg[3 * i + 0], 64.0f, 63.5f);
        float iy = fmaf(fg[3 * i + 1], 64.0f, 63.5f);
        float iz = fmaf(fg[3 * i + 2], 64.0f, 63.5f);
        int xb = (int)floorf(ix) + 1;
        int yb = (int)floorf(iy) + 1;
        int zb = (int)floorf(iz) + 1;                  // [0,128]
        gb[i] = (u32)tbl[(zb * TD + yb) * TD + xb];
    }
    asm volatile("s_waitcnt lgkmcnt(0)" ::: "memory");
    __builtin_amdgcn_s_barrier();                      // fill A visible
    jloop(0);
    asm volatile("s_waitcnt lgkmcnt(0)" ::: "memory"); // pass-A reads done
    __builtin_amdgcn_s_barrier();                      // safe to overwrite
    // ================= pass B =================
    {
        const ux4* src = (const ux4*)(mask32 + 32256);
        ux4* dst = (ux4*)lds;
#pragma unroll
        for (int i = 0; i < 8; ++i) dst[tid + 1024 * i] = src[tid + 1024 * i];
        if (tid < 128) dst[8192 + tid] = src[8192 + tid];
        if (tid == 0) lds[33280] = 0;                  // straddle pad
    }
#pragma unroll
    for (int i = 4; i < 8; ++i) {
        float ix = fmaf(fg[3 * i + 0], 64.0f, 63.5f);
        float iy = fmaf(fg[3 * i + 1], 64.0f, 63.5f);
        float iz = fmaf(fg[3 * i + 2], 64.0f, 63.5f);
        int xb = (int)floorf(ix) + 1;
        int yb = (int)floorf(iy) + 1;
        int zb = (int)floorf(iz) + 1;
        gb[i] = (u32)tbl[(zb * TD + yb) * TD + xb];
    }
    asm volatile("s_waitcnt lgkmcnt(0)" ::: "memory");
    __builtin_amdgcn_s_barrier();                      // fill B visible
    jloop(1);

    // ---- consume gathered bytes (weights recomputed from qg)
    float og[8];
#pragma unroll
    for (int i = 0; i < 8; ++i) {
        float ix = fmaf(fg[3 * i + 0], 64.0f, 63.5f);
        float iy = fmaf(fg[3 * i + 1], 64.0f, 63.5f);
        float iz = fmaf(fg[3 * i + 2], 64.0f, 63.5f);
        float fx = floorf(ix), fy = floorf(iy), fz = floorf(iz);
        float gwx = ix - fx, gwy = iy - fy, gwz = iz - fz;
        unsigned byte = gb[i];
        float v0 = (float)( byte       & 1u);
        float v1 = (float)((byte >> 1) & 1u);
        float v2 = (float)((byte >> 2) & 1u);
        float v3 = (float)((byte >> 3) & 1u);
        float v4 = (float)((byte >> 4) & 1u);
        float v5 = (float)((byte >> 5) & 1u);
        float v6 = (float)((byte >> 6) & 1u);
        float v7 = (float)((byte >> 7) & 1u);
        float c00 = v0 + gwx * (v1 - v0);
        float c10 = v2 + gwx * (v3 - v2);
        float c01 = v4 + gwx * (v5 - v4);
        float c11 = v6 + gwx * (v7 - v6);
        float c0  = c00 + gwy * (c10 - c00);
        float c1  = c01 + gwy * (c11 - c01);
        og[i] = c0 + gwz * (c1 - c0);
    }

    fx4* o4 = (fx4*)out;
    fx4 r0 = {o[0], o[1], o[2], o[3]};
    fx4 r1 = {o[4], o[5], o[6], o[7]};
    fx4 g0 = {og[0], og[1], og[2], og[3]};
    fx4 g1 = {og[4], og[5], og[6], og[7]};
    __builtin_nontemporal_store(r0, &o4[2 * Ts]);
    __builtin_nontemporal_store(r1, &o4[2 * Ts + 1]);
    __builtin_nontemporal_store(g0, &o4[2 * Tg]);
    __builtin_nontemporal_store(g1, &o4[2 * Tg + 1]);
}

// ------------------------------------------------- fallback sampler ------
__global__ __launch_bounds__(256)
void sample_packed(const unsigned char* __restrict__ tbl,
                   const float* __restrict__ coords,
                   float* __restrict__ out, int nt) {
    int t = blockIdx.x * blockDim.x + threadIdx.x;
    if (t >= nt) return;
    const fx4* c4 = (const fx4*)coords;
    fx4 q[6];
#pragma unroll
    for (int j = 0; j < 6; ++j) q[j] = __builtin_nontemporal_load(&c4[6 * t + j]);
    const float* f = (const float*)q;
    float wxa[8], wya[8], wza[8];
    int addr[8];
#pragma unroll
    for (int i = 0; i < 8; ++i) {
        float ix = fmaf(f[3 * i + 0], 64.0f, 63.5f);
        float iy = fmaf(f[3 * i + 1], 64.0f, 63.5f);
        float iz = fmaf(f[3 * i + 2], 64.0f, 63.5f);
        float fx = floorf(ix), fy = floorf(iy), fz = floorf(iz);
        wxa[i] = ix - fx; wya[i] = iy - fy; wza[i] = iz - fz;
        int xb = (int)fx + 1, yb = (int)fy + 1, zb = (int)fz + 1;
        addr[i] = (zb * TD + yb) * TD + xb;
    }
    unsigned bytes[8];
#pragma unroll
    for (int i = 0; i < 8; ++i) bytes[i] = (unsigned)tbl[addr[i]];
    float o[8];
#pragma unroll
    for (int i = 0; i < 8; ++i) {
        unsigned byte = bytes[i];
        float wx = wxa[i], wy = wya[i], wz = wza[i];
        float v0 = (float)( byte       & 1u);
        float v1 = (float)((byte >> 1) & 1u);
        float v2 = (float)((byte >> 2) & 1u);
        float v3 = (float)((byte >> 3) & 1u);
        float v4 = (float)((byte >> 4) & 1u);
        float v5 = (float)((byte >> 5) & 1u);
        float v6 = (float)((byte >> 6) & 1u);
        float v7 = (float)((byte >> 7) & 1u);
        float c00 = v0 + wx * (v1 - v0);
        float c10 = v2 + wx * (v3 - v2);
        float c01 = v4 + wx * (v5 - v4);
        float c11 = v6 + wx * (v7 - v6);
        float c0  = c00 + wy * (c10 - c00);
        float c1  = c01 + wy * (c11 - c01);
        o[i] = c0 + wz * (c1 - c0);
    }
    fx4* o4 = (fx4*)out;
    fx4 r0 = {o[0], o[1], o[2], o[3]};
    fx4 r1 = {o[4], o[5], o[6], o[7]};
    __builtin_nontemporal_store(r0, &o4[2 * t + 0]);
    __builtin_nontemporal_store(r1, &o4[2 * t + 1]);
}

// ------------------------------------------------- fallback: LDS slab ----
__global__ __launch_bounds__(1024, 4)
void sample_2p(const u32* __restrict__ mask32,
               const float* __restrict__ coords,
               float* __restrict__ out) {
    extern __shared__ u32 lds[];
    const int tid = threadIdx.x;
    const int T = blockIdx.x * 1024 + tid;
    const fx4* c4 = (const fx4*)coords;
    fx4 q[6];
#pragma unroll
    for (int j = 0; j < 6; ++j) q[j] = c4[6 * T + j];
    const float* f = (const float*)q;
    u32 pack1[8];
    u32 AM = 0;
    float wx[8], wy[8], wz[8], o[8];
#pragma unroll
    for (int j = 0; j < 8; ++j) {
        float ix = fmaf(f[3 * j + 0], 64.0f, 63.5f);
        float iy = fmaf(f[3 * j + 1], 64.0f, 63.5f);
        float iz = fmaf(f[3 * j + 2], 64.0f, 63.5f);
        float fx = floorf(ix), fy = floorf(iy), fz = floorf(iz);
        float w0 = ix - fx;
        wy[j] = iy - fy; wz[j] = iz - fz;
        int x0 = (int)fx, y0 = (int)fy, z0 = (int)fz;
        int zb = z0 + 1;
        bool flip = (x0 < 0);
        wx[j] = flip ? 1.0f - w0 : w0;
        int xc = flip ? 0 : x0;
        int sft = xc & 31;
        u32 xm = ((u32)x0 <= 126u) ? 3u : 1u;
        u32 vy0 = (u32)(y0 >= 0);
        u32 vy1 = (u32)((u32)y0 <= 126u);
        u32 a0 = vy0 ? xm : 0u;
        u32 a1 = vy1 ? xm : 0u;
        u32 am = a0 | (a1 << 2);
        u32 dyf = vy0 & vy1;
        int y0c = y0 < 0 ? 0 : y0;
        int z0c = z0 < 0 ? 0 : z0;
        u32 RA = (u32)(((z0c << 7) + y0c) * 4 + (xc >> 5));
        pack1[j] = RA | ((u32)sft << 16) | ((u32)zb << 21) | (dyf << 29);
        AM |= am << (4 * j);
        o[j] = 0.0f;
    }
#pragma unroll 1
    for (int s = 0; s < 2; ++s) {
        const int base_w = s ? 32256 : 0;
        const int nv4    = s ? 8320 : 8192;
        __syncthreads();
        {
            const ux4* src = (const ux4*)(mask32 + base_w);
            ux4* dst = (ux4*)lds;
            for (int i = tid; i < nv4; i += 1024) dst[i] = src[i];
            if (s && tid == 0) lds[33280] = 0;
        }
        __syncthreads();
#pragma unroll
        for (int j = 0; j < 8; ++j) {
            u32 pv = pack1[j];
            int zb = (int)((pv >> 21) & 0xFF);
            if ((zb < 64) != (s == 0)) continue;
            int la  = (int)(pv & 0xFFFF) - base_w;
            int sft = (int)((pv >> 16) & 31);
            int dyw = (int)((pv >> 27) & 4);
            bool edge = s ? (zb == 128) : (zb == 0);
            int dz = edge ? 0 : 512;
            u32 amv = (AM >> (4 * j)) & 15u;
            u32 glo = amv, ghi = amv;
            if (s) ghi = edge ? 0u : amv;
            else   glo = edge ? 0u : amv;
            int l0 = la, l1 = la + dyw, l2 = la + dz, l3 = la + dz + dyw;
            u32 w00 = lds[l0], w01 = lds[l0 + 1];
            u32 w10 = lds[l1], w11 = lds[l1 + 1];
            u32 w20 = lds[l2], w21 = lds[l2 + 1];
            u32 w30 = lds[l3], w31 = lds[l3 + 1];
            u32 t0b = __builtin_amdgcn_alignbit(w01, w00, (u32)sft) & (glo & 3u);
            u32 t1b = __builtin_amdgcn_alignbit(w11, w10, (u32)sft) & ((glo >> 2) & 3u);
            u32 t2b = __builtin_amdgcn_alignbit(w21, w20, (u32)sft) & (ghi & 3u);
            u32 t3b = __builtin_amdgcn_alignbit(w31, w30, (u32)sft) & ((ghi >> 2) & 3u);
            float w = wx[j];
            int b0 = (int)(t0b & 1u), b1 = (int)(t1b & 1u);
            int b2 = (int)(t2b & 1u), b3 = (int)(t3b & 1u);
            float r00 = fmaf(w, (float)((int)(t0b >> 1) - b0), (float)b0);
            float r01 = fmaf(w, (float)((int)(t1b >> 1) - b1), (float)b1);
            float r10 = fmaf(w, (float)((int)(t2b >> 1) - b2), (float)b2);
            float r11 = fmaf(w, (float)((int)(t3b >> 1) - b3), (float)b3);
            float cy0 = fmaf(wy[j], r01 - r00, r00);
            float cy1 = fmaf(wy[j], r11 - r10, r10);
            o[j] = fmaf(wz[j], cy1 - cy0, cy0);
        }
    }
    fx4* o4 = (fx4*)out;
    fx4 r0 = {o[0], o[1], o[2], o[3]};
    fx4 r1 = {o[4], o[5], o[6], o[7]};
    o4[2 * T]     = r0;
    o4[2 * T + 1] = r1;
}

// -------------------------------------------------------------- launch ----
extern "C" void kernel_launch(void* const* d_in, const int* in_sizes, int n_in,
                              void* d_out, int out_size, void* d_ws, size_t ws_size,
                              hipStream_t stream) {
    const float* grid   = (const float*)d_in[0];
    const float* coords = (const float*)d_in[1];
    float* out = (float*)d_out;
    int npts = in_sizes[1] / 3;                          // 8,388,608
    int vox = GS * GS * GS;

    u64* mask = (u64*)d_ws;                              // 256 KB @ offset 0

    if (ws_size >= WS_FB && npts == NPTS_FULL) {
        // PRIMARY: fused prep + same-wave hybrid (2 nodes).
        (void)hipFuncSetAttribute((const void*)sample_hyb,
                                  hipFuncAttributeMaxDynamicSharedMemorySize,
                                  (int)SLAB_LDS);
        int nb = 0;
        hipError_t oe = hipOccupancyMaxActiveBlocksPerMultiprocessor(
            &nb, sample_hyb, 1024, SLAB_LDS);
        unsigned char* tbl = (unsigned char*)d_ws + TBL_OFF;
        prep2_kernel<<<PREP_BLOCKS, 256, 0, stream>>>(grid, mask, tbl);
        if (oe == hipSuccess && nb >= 1) {
            sample_hyb<<<512, 1024, SLAB_LDS, stream>>>(
                (const u32*)mask, tbl, coords, out);
        } else {
            int nt = npts / 8;
            sample_packed<<<(nt + 255) / 256, 256, 0, stream>>>(tbl, coords, out, nt);
        }
        return;
    }

    if (ws_size >= WS_FB && (npts & 7) == 0) {
        // FALLBACK: fused prep + pure byte-table path.
        unsigned char* tbl = (unsigned char*)d_ws + TBL_OFF;
        prep2_kernel<<<PREP_BLOCKS, 256, 0, stream>>>(grid, mask, tbl);
        int nt = npts / 8;
        sample_packed<<<(nt + 255) / 256, 256, 0, stream>>>(tbl, coords, out, nt);
        return;
    }

    if (ws_size >= MASK_BYTES && npts == 1024 * 8192) {
        // FALLBACK: tiny workspace — 2-pass LDS slab.
        (void)hipFuncSetAttribute((const void*)sample_2p,
                                  hipFuncAttributeMaxDynamicSharedMemorySize,
                                  (int)SLAB_LDS);
        int nb = 0;
        hipError_t oe = hipOccupancyMaxActiveBlocksPerMultiprocessor(
            &nb, sample_2p, 1024, SLAB_LDS);
        if (oe == hipSuccess && nb >= 1) {
            bitpack_kernel<<<vox / 256, 256, 0, stream>>>(grid, mask);
            sample_2p<<<1024, 1024, SLAB_LDS, stream>>>((const u32*)mask, coords, out);
        }
    }
}